// Round 9
// baseline (16.057 us; speedup 1.0000x reference)
//
#include <hip/hip_runtime.h>

// RankNetLoss, n=8192.
// sum over ordered pairs i!=j of [0.5*(1-S)*d + log2(1+exp(-d))].
// The 0.5*(1-S)*d term cancels exactly (S symmetric, d antisymmetric) -> labels irrelevant.
// Fold ordered -> unordered pairs, pre-scaled scores s' = s/ln2:
//   a = |s'_i - s'_j|;  pair cost = a + 2*log2(1+2^{-a}).
// Batch the logs: sum log2(1+e) = log2(prod(1+e)), factors in [1,2];
// 4 chains x 16 factors -> prod <= 2^16 (fp32-safe), and FMA latency hidden.
// Inner loop per 4 pairs: 1 ds_read_b128 + 4x(v_sub, v_add|abs|, v_fmac, v_exp).
// Two kernels, dense part[] (1056+ simultaneous same-address atomics cost ~8us
// -- measured round 6; cooperative grid-sync spin would cost similarly).

static constexpr int TI = 256;      // i-extent per block (= block threads)
static constexpr int TJ = 64;       // j-extent per block
static constexpr int R  = TI / TJ;  // 4

__global__ __launch_bounds__(256, 8) void rn_main(const float* __restrict__ s,
                                                  float* __restrict__ part,
                                                  int n, int gx) {
    // Decode linear active-tile id -> (it, jt). Row it has tiles jt in
    // [it*R, gx-1], count = gx - it*R. Uniform -> scalar loop.
    int rem = blockIdx.x;
    int it = 0;
    while (rem >= gx - it * R) { rem -= gx - it * R; ++it; }
    const int jt = it * R + rem;

    const int t = threadIdx.x;
    const int i = it * TI + t;
    const int j0 = jt * TJ;

    constexpr float INV_LN2 = 1.44269504088896340736f;

    __shared__ __align__(16) float sj[TJ];   // pre-scaled: s[j]/ln2
    if (t < TJ) {
        int j = j0 + t;
        sj[t] = ((j < n) ? s[j] : 0.0f) * INV_LN2;
    }
    __syncthreads();

    const float si = ((i < n) ? s[i] : 0.0f) * INV_LN2;

    float a0 = 0.0f, a1 = 0.0f;                          // sum a, 2 chains
    float p0 = 1.0f, p1 = 1.0f, p2 = 1.0f, p3 = 1.0f;    // prod(1+e), 4 chains

    const bool clean = (jt >= (it + 1) * R) && (j0 + TJ <= n) && (it * TI + TI <= n);
    if (clean) {
        #pragma unroll
        for (int jj = 0; jj < TJ; jj += 4) {
            float4 v = *reinterpret_cast<const float4*>(&sj[jj]);  // ds_read_b128, uniform
            float x0 = si - v.x, x1 = si - v.y, x2 = si - v.z, x3 = si - v.w;
            float e0 = __builtin_amdgcn_exp2f(-fabsf(x0));  // -abs = free src mod
            float e1 = __builtin_amdgcn_exp2f(-fabsf(x1));
            float e2 = __builtin_amdgcn_exp2f(-fabsf(x2));
            float e3 = __builtin_amdgcn_exp2f(-fabsf(x3));
            a0 += fabsf(x0);  a1 += fabsf(x1);
            a0 += fabsf(x2);  a1 += fabsf(x3);
            p0 = __builtin_fmaf(p0, e0, p0);               // *= (1+e)
            p1 = __builtin_fmaf(p1, e1, p1);
            p2 = __builtin_fmaf(p2, e2, p2);
            p3 = __builtin_fmaf(p3, e3, p3);
        }
    } else {
        #pragma unroll
        for (int jj = 0; jj < TJ; jj += 4) {
            float4 v = *reinterpret_cast<const float4*>(&sj[jj]);
            int ja = j0 + jj;
            float x0 = si - v.x, x1 = si - v.y, x2 = si - v.z, x3 = si - v.w;
            float e0 = __builtin_amdgcn_exp2f(-fabsf(x0));
            float e1 = __builtin_amdgcn_exp2f(-fabsf(x1));
            float e2 = __builtin_amdgcn_exp2f(-fabsf(x2));
            float e3 = __builtin_amdgcn_exp2f(-fabsf(x3));
            bool ok0 = (ja + 0 > i) && (ja + 0 < n) && (i < n);
            bool ok1 = (ja + 1 > i) && (ja + 1 < n) && (i < n);
            bool ok2 = (ja + 2 > i) && (ja + 2 < n) && (i < n);
            bool ok3 = (ja + 3 > i) && (ja + 3 < n) && (i < n);
            a0 += ok0 ? fabsf(x0) : 0.0f;  a1 += ok1 ? fabsf(x1) : 0.0f;
            a0 += ok2 ? fabsf(x2) : 0.0f;  a1 += ok3 ? fabsf(x3) : 0.0f;
            p0 = __builtin_fmaf(p0, ok0 ? e0 : 0.0f, p0);  // masked factor = 1
            p1 = __builtin_fmaf(p1, ok1 ? e1 : 0.0f, p1);
            p2 = __builtin_fmaf(p2, ok2 ? e2 : 0.0f, p2);
            p3 = __builtin_fmaf(p3, ok3 ? e3 : 0.0f, p3);
        }
    }
    float lg = (__builtin_amdgcn_logf(p0) + __builtin_amdgcn_logf(p1)) +
               (__builtin_amdgcn_logf(p2) + __builtin_amdgcn_logf(p3));
    float total = __builtin_fmaf(2.0f, lg, a0 + a1);

    // wave reduce (64 lanes)
    for (int off = 32; off > 0; off >>= 1)
        total += __shfl_down(total, off, 64);

    __shared__ float wpart[TI / 64];
    if ((t & 63) == 0) wpart[t >> 6] = total;
    __syncthreads();
    if (t == 0) {
        float b = 0.0f;
        #pragma unroll
        for (int k = 0; k < TI / 64; ++k) b += wpart[k];
        part[blockIdx.x] = b;   // dense, no atomics, no pre-zero needed
    }
}

__global__ __launch_bounds__(1024) void rn_final(const float* __restrict__ part,
                                                 float* __restrict__ out,
                                                 int nblocks, float inv_pairs) {
    const int t = threadIdx.x;
    float a = 0.0f;
    for (int k = t; k < nblocks; k += 1024) a += part[k];
    for (int off = 32; off > 0; off >>= 1)
        a += __shfl_down(a, off, 64);
    __shared__ float wp[16];
    if ((t & 63) == 0) wp[t >> 6] = a;
    __syncthreads();
    if (t == 0) {
        float b = 0.0f;
        #pragma unroll
        for (int k = 0; k < 16; ++k) b += wp[k];
        out[0] = b * inv_pairs;
    }
}

extern "C" void kernel_launch(void* const* d_in, const int* in_sizes, int n_in,
                              void* d_out, int out_size, void* d_ws, size_t ws_size,
                              hipStream_t stream) {
    const float* s = (const float*)d_in[0];
    // d_in[1] (labels) is mathematically irrelevant (antisymmetric term cancels).
    const int n = in_sizes[0];

    float* part = (float*)d_ws;
    float* out = (float*)d_out;

    const int gx = (n + TJ - 1) / TJ;   // j-tiles (128 at n=8192)
    const int gy = (n + TI - 1) / TI;   // i-tiles (32)

    int nactive = 0;
    for (int it = 0; it < gy; ++it) {
        int c = gx - it * R;
        if (c > 0) nactive += c;
    }

    rn_main<<<nactive, TI, 0, stream>>>(s, part, n, gx);

    const double npairs = (double)n * (double)(n - 1);
    rn_final<<<1, 1024, 0, stream>>>(part, out, nactive, (float)(1.0 / npairs));
}

// Round 10
// 14.539 us; speedup vs baseline: 1.1044x; 1.1044x over previous
//
#include <hip/hip_runtime.h>

// RankNetLoss, n=8192.
// sum over ordered pairs i!=j of [0.5*(1-S)*d + log2(1+exp(-d))].
// The 0.5*(1-S)*d term cancels exactly (S symmetric, d antisymmetric) -> labels irrelevant.
// Fold ordered -> unordered pairs, work in log2 domain with PRE-SCALED scores
// (s' = s/ln2):  a = |s'_i - s'_j|;  pair cost = a + 2*log2(1+2^{-a}).
// Batch the logs: sum_j log2(1+e_j) = log2( prod_j (1+e_j) ), factors in [1,2],
// <= 32 factors/chain -> prod <= 2^32 (fp32-safe).
// Inner loop per pair: ds_read_b32 + v_sub + v_add(|x|) + v_fmac + v_exp(-|x|).
// Best measured config (round 8: 14.74us). Structural alternatives measured and
// rejected: single-kernel atomic tail +11.6us (r6), TJ=128 +2.4us (r7),
// float4+4-chain full unroll +1.3us (r9).

static constexpr int TI = 256;      // i-extent per block (= block threads)
static constexpr int TJ = 64;       // j-extent per block
static constexpr int R  = TI / TJ;  // 4

__global__ __launch_bounds__(256, 8) void rn_main(const float* __restrict__ s,
                                                  float* __restrict__ part,
                                                  int n, int gx) {
    // Decode linear active-tile id -> (it, jt). Row it has tiles jt in
    // [it*R, gx-1], count = gx - it*R. Uniform -> scalar loop.
    int rem = blockIdx.x;
    int it = 0;
    while (rem >= gx - it * R) { rem -= gx - it * R; ++it; }
    const int jt = it * R + rem;

    const int t = threadIdx.x;
    const int i = it * TI + t;
    const int j0 = jt * TJ;

    constexpr float INV_LN2 = 1.44269504088896340736f;

    __shared__ float sj[TJ];                 // pre-scaled: s[j]/ln2
    if (t < TJ) {
        int j = j0 + t;
        sj[t] = ((j < n) ? s[j] : 0.0f) * INV_LN2;
    }
    __syncthreads();

    const float si = ((i < n) ? s[i] : 0.0f) * INV_LN2;

    float accA = 0.0f;                 // sum a  (= sum |d|/ln2)
    float prod0 = 1.0f, prod1 = 1.0f;  // prod (1 + 2^{-a}), two chains for ILP

    const bool clean = (jt >= (it + 1) * R) && (j0 + TJ <= n) && (it * TI + TI <= n);
    if (clean) {
        #pragma unroll 8
        for (int jj = 0; jj < TJ; jj += 2) {
            float x0 = si - sj[jj];                       // uniform ds_read -> broadcast
            float x1 = si - sj[jj + 1];
            float e0 = __builtin_amdgcn_exp2f(-fabsf(x0)); // -abs = free src mod
            float e1 = __builtin_amdgcn_exp2f(-fabsf(x1));
            accA += fabsf(x0);                             // abs = free src mod
            accA += fabsf(x1);
            prod0 = __builtin_fmaf(prod0, e0, prod0);      // *= (1+e0)
            prod1 = __builtin_fmaf(prod1, e1, prod1);
        }
    } else {
        #pragma unroll 8
        for (int jj = 0; jj < TJ; jj += 2) {
            int ja = j0 + jj, jb = j0 + jj + 1;
            float x0 = si - sj[jj];
            float x1 = si - sj[jj + 1];
            float e0 = __builtin_amdgcn_exp2f(-fabsf(x0));
            float e1 = __builtin_amdgcn_exp2f(-fabsf(x1));
            bool ok0 = (ja > i) && (ja < n) && (i < n);
            bool ok1 = (jb > i) && (jb < n) && (i < n);
            accA += ok0 ? fabsf(x0) : 0.0f;
            accA += ok1 ? fabsf(x1) : 0.0f;
            prod0 = __builtin_fmaf(prod0, ok0 ? e0 : 0.0f, prod0);  // masked factor = 1
            prod1 = __builtin_fmaf(prod1, ok1 ? e1 : 0.0f, prod1);
        }
    }
    float total = __builtin_fmaf(2.0f,
                                 __builtin_amdgcn_logf(prod0) + __builtin_amdgcn_logf(prod1),
                                 accA);

    // wave reduce (64 lanes)
    for (int off = 32; off > 0; off >>= 1)
        total += __shfl_down(total, off, 64);

    __shared__ float wpart[TI / 64];
    if ((t & 63) == 0) wpart[t >> 6] = total;
    __syncthreads();
    if (t == 0) {
        float b = 0.0f;
        #pragma unroll
        for (int k = 0; k < TI / 64; ++k) b += wpart[k];
        part[blockIdx.x] = b;   // dense, no atomics, no pre-zero needed
    }
}

__global__ __launch_bounds__(1024) void rn_final(const float* __restrict__ part,
                                                 float* __restrict__ out,
                                                 int nblocks, float inv_pairs) {
    const int t = threadIdx.x;
    float a = 0.0f;
    for (int k = t; k < nblocks; k += 1024) a += part[k];
    for (int off = 32; off > 0; off >>= 1)
        a += __shfl_down(a, off, 64);
    __shared__ float wp[16];
    if ((t & 63) == 0) wp[t >> 6] = a;
    __syncthreads();
    if (t == 0) {
        float b = 0.0f;
        #pragma unroll
        for (int k = 0; k < 16; ++k) b += wp[k];
        out[0] = b * inv_pairs;
    }
}

extern "C" void kernel_launch(void* const* d_in, const int* in_sizes, int n_in,
                              void* d_out, int out_size, void* d_ws, size_t ws_size,
                              hipStream_t stream) {
    const float* s = (const float*)d_in[0];
    // d_in[1] (labels) is mathematically irrelevant (antisymmetric term cancels).
    const int n = in_sizes[0];

    float* part = (float*)d_ws;
    float* out = (float*)d_out;

    const int gx = (n + TJ - 1) / TJ;   // j-tiles (128 at n=8192)
    const int gy = (n + TI - 1) / TI;   // i-tiles (32)

    int nactive = 0;
    for (int it = 0; it < gy; ++it) {
        int c = gx - it * R;
        if (c > 0) nactive += c;
    }

    rn_main<<<nactive, TI, 0, stream>>>(s, part, n, gx);

    const double npairs = (double)n * (double)(n - 1);
    rn_final<<<1, 1024, 0, stream>>>(part, out, nactive, (float)(1.0 / npairs));
}